// Round 15
// baseline (106.022 us; speedup 1.0000x reference)
//
#include <hip/hip_runtime.h>
#include <hip/hip_bf16.h>
#include <hip/hip_fp8.h>
#include <stdint.h>

// Problem: N=4096 rows, D=768 dims.
//   dist[i][j] = ||A_i - P_j||;  scores = 50 - dist;  loss = mean_i(-log_softmax(scores)_ii)
// Fixed-shift softmax (scores <= 50 always): loss_i = dist_ii + log(sum_j exp(-dist_ij))
// R31 = R21 (verified best 101.7/101.9us) with gemm_fused widened to 1024 threads
// (16 waves, wave grid 8m x 2n, 32x64 wave tiles) at the SAME 256x128 tile and
// SAME LDS (72KB, triple-buffered lead-2 counted-vmcnt):
//   - 2 blocks/CU x 16 waves = 32 waves/CU = 100% occupancy (R21: 16 = 50%).
//     Occupancy is the only lever that has paid on this problem (R18, R19).
//   - VGPR engineered to <=64 for 8 waves/SIMD (launch_bounds(1024,8)): acc[2][4]
//     =32, bv 16, av loaded per-mi (4 live), aOff/bOff single base + compile-time
//     +1024 steps (slot rotation invariant under R->R+16: 8=0 mod 4).
//   - staging: 1 A-chunk/thread; B only waves 0-7 -> wave-uniform vmcnt(2)/(1).
// Failed grafts (do not retry): 2-phase split (R22), fused finalize (R23),
// MX-fp8 (R17 occupancy-bound / R26 spill-bound).

#define N_ROWS 4096
#define D_DIM  768
#define NITER (D_DIM / 64)               // 12 (BK=64 fp8 bytes)
#define ABUF  (256 * 64)                 // 16 KB per buffer (A)
#define BBUF  (128 * 64)                 // 8 KB per buffer (B)

typedef float f32x4 __attribute__((ext_vector_type(4)));
typedef int   i32x4 __attribute__((ext_vector_type(4)));

// ---------------- kernel 1: fp32 -> fp8 e4m3 cast (k-permuted) + norms + zero S --
// Within each 64B block (16 words): granule gw = w>>1 -> gp = ((gw&3)<<1)|(gw>>2).
__global__ __launch_bounds__(256) void cvt_norms(
        const float* __restrict__ A, const float* __restrict__ P,
        uint8_t* __restrict__ A8, uint8_t* __restrict__ P8,
        float* __restrict__ a2, float* __restrict__ p2, float* __restrict__ S) {
    const int t = threadIdx.x, lane = t & 63, wave = t >> 6;
    const int row = blockIdx.x * 4 + wave;
    const float* src = blockIdx.y ? P : A;
    uint8_t* dst = blockIdx.y ? P8 : A8;
    float* nrm = blockIdx.y ? p2 : a2;

    const float4* s4 = (const float4*)src + (size_t)row * (D_DIM / 4);
    uint32_t* d4 = (uint32_t*)dst + (size_t)row * (D_DIM / 4);   // row base
    float s = 0.0f;
#pragma unroll
    for (int c = 0; c < 3; c++) {
        const int wf = c * 64 + lane;            // word index in row (0..191)
        float4 v = s4[wf];
        s += v.x * v.x + v.y * v.y + v.z * v.z + v.w * v.w;
        union { uint32_t u; uint8_t b[4]; } pk;
        pk.b[0] = __hip_fp8_e4m3(v.x).__x;
        pk.b[1] = __hip_fp8_e4m3(v.y).__x;
        pk.b[2] = __hip_fp8_e4m3(v.z).__x;
        pk.b[3] = __hip_fp8_e4m3(v.w).__x;
        const int kb = wf >> 4, w16 = wf & 15;
        const int gw = w16 >> 1, h = w16 & 1;
        const int gp = ((gw & 3) << 1) | (gw >> 2);     // [0,4,1,5,2,6,3,7] order
        d4[(kb << 4) + (gp << 1) + h] = pk.u;           // relative to row base
    }
    for (int off = 32; off; off >>= 1) s += __shfl_down(s, off);
    if (lane == 0) {
        nrm[row] = s;
        if (blockIdx.y == 0) S[row] = 0.0f;
    }
}

// ---------------- kernel 2: triple-buffered fp8 MFMA GEMM + softmax epilogue -----
__device__ __forceinline__ void g2l16(const void* g, void* l) {
    __builtin_amdgcn_global_load_lds(
        (const __attribute__((address_space(1))) void*)g,
        (__attribute__((address_space(3))) void*)l, 16, 0, 0);
}

__global__ __launch_bounds__(1024, 8) void gemm_fused(
        const uint8_t* __restrict__ A8, const uint8_t* __restrict__ P8,
        const float* __restrict__ a2, const float* __restrict__ p2,
        float* __restrict__ S, float* __restrict__ Dd) {
    __shared__ __align__(16) uint8_t As[3 * ABUF];   // 3 x 16 KB
    __shared__ __align__(16) uint8_t Bs[3 * BBUF];   // 3 x 8 KB

    // XCD-bijective swizzle: 512 blocks round-robin across 8 XCDs; XCD x gets the
    // contiguous swz range [x*64,(x+1)*64) = 4 B-panels x all 16 A-panels.
    const int lin = blockIdx.x;
    const int swz = (lin & 7) * 64 + (lin >> 3);
    const int bm = swz & 15, bn = swz >> 4;          // bm: 256-row A panel, bn: 128-row B panel

    const int t = threadIdx.x;                       // 0..1023
    const int lane = t & 63, wave = t >> 6;          // 16 waves
    const int wm = wave >> 1, wn = wave & 1;         // 8m x 2n, 32x64 wave tiles

    f32x4 acc[2][4];
#pragma unroll
    for (int i = 0; i < 2; i++)
#pragma unroll
        for (int j = 0; j < 4; j++) acc[i][j] = (f32x4){0.f, 0.f, 0.f, 0.f};

    // staging: chunk q = t -> LDS row r = t>>2, slot t&3. Stored global chunk g:
    // slot = (g + (r>>1))&3 -> g = ((t&3) - (t>>3)) & 3. A: all 1024 threads
    // (rows 0..255); B: threads 0..511 (rows 0..127).
    const int gT = ((t & 3) - (t >> 3)) & 3;
    const size_t aBase = (size_t)(bm * 256 + (t >> 2)) * D_DIM + (size_t)gT * 16;
    const size_t bBase = (size_t)(bn * 128 + (t >> 2)) * D_DIM + (size_t)gT * 16;

    // LDS->frag base offsets (bytes). Row stride 64 B; slot (fq + (R>>1))&3.
    // mi/ni step = +16 rows = +1024 B, slot invariant ((R>>1)+8 == +0 mod 4).
    const int fr = lane & 15, fq = lane >> 4;
    const int Ra = wm * 32 + fr;                     // 0..255 (mi=0 row)
    const int aOff0 = Ra * 64 + ((fq + (Ra >> 1)) & 3) * 16;
    const int Rb = wn * 64 + fr;                     // 0..127 (ni=0 row)
    const int bOff0 = Rb * 64 + ((fq + (Rb >> 1)) & 3) * 16;

#define STAGE(K2, SEL)                                                            \
    do {                                                                          \
        const int k0_ = (K2) * 64;                                                \
        g2l16(A8 + aBase + k0_, &As[(SEL) * ABUF + t * 16]);                      \
        if (t < 512) g2l16(P8 + bBase + k0_, &Bs[(SEL) * BBUF + t * 16]);         \
    } while (0)

    STAGE(0, 0);
    STAGE(1, 1);

    int s0 = 0;                                  // buffer holding tile k
    for (int k = 0; k < NITER; k++) {
        // Drain tile k's loads (issued at iter k-2); tile k+1's stay in flight.
        // Waves 0-7 carry 2 loads/tile (A+B), waves 8-15 carry 1 (A only).
        if (k == NITER - 1)  asm volatile("s_waitcnt vmcnt(0)" ::: "memory");
        else if (wave < 8)   asm volatile("s_waitcnt vmcnt(2)" ::: "memory");
        else                 asm volatile("s_waitcnt vmcnt(1)" ::: "memory");
        asm volatile("s_barrier" ::: "memory");
        if (k + 2 < NITER) {
            int s2 = s0 + 2; if (s2 >= 3) s2 -= 3;
            STAGE(k + 2, s2);                    // WAR-safe: buf read in iter k-1
        }

        const int lbA = s0 * ABUF, lbB = s0 * BBUF;
        i32x4 bv[4];
#pragma unroll
        for (int ni = 0; ni < 4; ni++)
            bv[ni] = *(const i32x4*)&Bs[lbB + bOff0 + ni * 1024];
#pragma unroll
        for (int mi = 0; mi < 2; mi++) {
            const i32x4 av = *(const i32x4*)&As[lbA + aOff0 + mi * 1024];
#pragma unroll
            for (int step = 0; step < 2; step++) {
                const long long afh = ((const long long*)&av)[step];
#pragma unroll
                for (int ni = 0; ni < 4; ni++) {
                    const long long bfh = ((const long long*)&bv[ni])[step];
                    acc[mi][ni] = __builtin_amdgcn_mfma_f32_16x16x32_fp8_fp8(
                        afh, bfh, acc[mi][ni], 0, 0, 0);
                }
            }
        }
        s0 = (s0 == 2) ? 0 : s0 + 1;
    }
#undef STAGE

    // ---- epilogue: dist -> exp(-dist), per-row partial sums, diagonal capture ----
    // C/D layout (16x16, shape-determined): col = lane&15, row = (lane>>4)*4 + reg
    float p2v[4];
#pragma unroll
    for (int ni = 0; ni < 4; ni++)
        p2v[ni] = p2[bn * 128 + wn * 64 + ni * 16 + fr];
    const int colBase = bn * 128 + wn * 64 + fr;

#pragma unroll
    for (int mi = 0; mi < 2; mi++) {
#pragma unroll
        for (int r = 0; r < 4; r++) {
            const int gi = bm * 256 + wm * 32 + mi * 16 + fq * 4 + r;
            const float a2v = a2[gi];
            float rs = 0.0f;
#pragma unroll
            for (int ni = 0; ni < 4; ni++) {
                const float cross = acc[mi][ni][r];
                const float sq = a2v + p2v[ni] - 2.0f * cross;
                const float dist = sqrtf(fmaxf(sq, 0.0f) + 1e-12f);
                const int gj = colBase + ni * 16;
                if (gi == gj) Dd[gi] = dist;
                rs += __expf(-dist);
            }
            rs += __shfl_xor(rs, 1);
            rs += __shfl_xor(rs, 2);
            rs += __shfl_xor(rs, 4);
            rs += __shfl_xor(rs, 8);
            if (fr == 0) atomicAdd(&S[gi], rs);
        }
    }
}

// ---------------- kernel 3: final reduce -> scalar -------------------------------
__global__ __launch_bounds__(1024) void finalize(
        const float* __restrict__ S, const float* __restrict__ Dd,
        float* __restrict__ out) {
    const int t = threadIdx.x;
    float s = 0.0f;
    for (int i = t; i < N_ROWS; i += 1024) s += Dd[i] + logf(S[i]);
    for (int off = 32; off; off >>= 1) s += __shfl_down(s, off);
    __shared__ float wsum[16];
    if ((t & 63) == 0) wsum[t >> 6] = s;
    __syncthreads();
    if (t == 0) {
        float acc = 0.0f;
#pragma unroll
        for (int w = 0; w < 16; w++) acc += wsum[w];
        out[0] = acc * (1.0f / N_ROWS);
    }
}

// ---------------- fallback (undersized workspace): naive fp32 --------------------
__global__ void zero_out1(float* __restrict__ out) {
    if (threadIdx.x == 0 && blockIdx.x == 0) out[0] = 0.0f;
}
__global__ void naive_row(const float* __restrict__ A, const float* __restrict__ P,
                          float* __restrict__ out) {
    __shared__ float arow[D_DIM];
    const int i = blockIdx.x, t = threadIdx.x;
    for (int c = t; c < D_DIM; c += 256) arow[c] = A[(size_t)i * D_DIM + c];
    __syncthreads();
    float sumexp = 0.0f, ddiag = 0.0f;
    for (int j = t; j < N_ROWS; j += 256) {
        const float* p = P + (size_t)j * D_DIM;
        float d2 = 0.0f;
        for (int c = 0; c < D_DIM; c++) { float df = arow[c] - p[c]; d2 += df * df; }
        float dist = sqrtf(fmaxf(d2, 0.0f) + 1e-12f);
        if (j == i) ddiag = dist;
        sumexp += __expf(-dist);
    }
    for (int off = 32; off; off >>= 1) {
        sumexp += __shfl_down(sumexp, off);
        ddiag  += __shfl_down(ddiag, off);
    }
    __shared__ float w1[4], w2[4];
    if ((t & 63) == 0) { w1[t >> 6] = sumexp; w2[t >> 6] = ddiag; }
    __syncthreads();
    if (t == 0) {
        float se = w1[0] + w1[1] + w1[2] + w1[3];
        float dd = w2[0] + w2[1] + w2[2] + w2[3];
        atomicAdd(out, (dd + logf(se)) * (1.0f / N_ROWS));
    }
}

extern "C" void kernel_launch(void* const* d_in, const int* in_sizes, int n_in,
                              void* d_out, int out_size, void* d_ws, size_t ws_size,
                              hipStream_t stream) {
    const float* A = (const float*)d_in[0];
    const float* P = (const float*)d_in[1];
    float* out = (float*)d_out;

    const size_t F8_BYTES = (size_t)N_ROWS * D_DIM;          // 3145728 per matrix
    const size_t V_BYTES  = (size_t)N_ROWS * sizeof(float);  // 16384
    const size_t NEED = 2 * F8_BYTES + 4 * V_BYTES;

    if (ws_size >= NEED) {
        char* ws = (char*)d_ws;
        uint8_t* A8 = (uint8_t*)(ws);
        uint8_t* P8 = (uint8_t*)(ws + F8_BYTES);
        float* a2 = (float*)(ws + 2 * F8_BYTES);
        float* p2 = (float*)(ws + 2 * F8_BYTES + V_BYTES);
        float* S  = (float*)(ws + 2 * F8_BYTES + 2 * V_BYTES);
        float* Dd = (float*)(ws + 2 * F8_BYTES + 3 * V_BYTES);

        hipLaunchKernelGGL(cvt_norms, dim3(N_ROWS / 4, 2), dim3(256), 0, stream,
                           A, P, A8, P8, a2, p2, S);
        hipLaunchKernelGGL(gemm_fused, dim3(512), dim3(1024), 0, stream,
                           A8, P8, a2, p2, S, Dd);
        hipLaunchKernelGGL(finalize, dim3(1), dim3(1024), 0, stream, S, Dd, out);
    } else {
        hipLaunchKernelGGL(zero_out1, dim3(1), dim3(64), 0, stream, out);
        hipLaunchKernelGGL(naive_row, dim3(N_ROWS), dim3(256), 0, stream, A, P, out);
    }
}

// Round 16
// 101.001 us; speedup vs baseline: 1.0497x; 1.0497x over previous
//
#include <hip/hip_runtime.h>
#include <hip/hip_bf16.h>
#include <hip/hip_fp8.h>
#include <stdint.h>

// Problem: N=4096 rows, D=768 dims.
//   dist[i][j] = ||A_i - P_j||;  scores = 50 - dist;  loss = mean_i(-log_softmax(scores)_ii)
// Fixed-shift softmax (scores <= 50 always): loss_i = dist_ii + log(sum_j exp(-dist_ij))
// R32 = REVERT to R21 (verified best: 101.7us R21, 101.9us R30). R31 post-mortem:
// 1024-thread/16-wave variant (100% occupancy target) regressed to 106.0us —
// halved per-wave MFMA work + 16-wave barrier domain + divergent B-staging cost
// more than the extra TLP returned. Occupancy ladder closed: 8 fat waves x 2
// blocks/CU is the optimum shape.
// Failed grafts (do not retry): 2-phase split (R22 +3.5), fused finalize (R23
// +3.9), MX-fp8 (R17/R26: occupancy- or spill-bound), 16 thin waves (R31 +4.2).
// R21 = 256x128 block, 8 waves (4m x 2n, 64x64 wave tiles), fp8 16x16x32,
// conflict-free 64B-row LDS ADD-swizzle, triple-buffered lead-2 vmcnt(3) K-loop,
// XCD-bijective block swizzle, exactly 2 blocks/CU (LDS 144KB), grid 512.

#define N_ROWS 4096
#define D_DIM  768
#define NITER (D_DIM / 64)               // 12 (BK=64 fp8 bytes)
#define ABUF  (256 * 64)                 // 16 KB per buffer (A)
#define BBUF  (128 * 64)                 // 8 KB per buffer (B)

typedef float f32x4 __attribute__((ext_vector_type(4)));
typedef int   i32x4 __attribute__((ext_vector_type(4)));

// ---------------- kernel 1: fp32 -> fp8 e4m3 cast (k-permuted) + norms + zero S --
// Within each 64B block (16 words): granule gw = w>>1 -> gp = ((gw&3)<<1)|(gw>>2).
__global__ __launch_bounds__(256) void cvt_norms(
        const float* __restrict__ A, const float* __restrict__ P,
        uint8_t* __restrict__ A8, uint8_t* __restrict__ P8,
        float* __restrict__ a2, float* __restrict__ p2, float* __restrict__ S) {
    const int t = threadIdx.x, lane = t & 63, wave = t >> 6;
    const int row = blockIdx.x * 4 + wave;
    const float* src = blockIdx.y ? P : A;
    uint8_t* dst = blockIdx.y ? P8 : A8;
    float* nrm = blockIdx.y ? p2 : a2;

    const float4* s4 = (const float4*)src + (size_t)row * (D_DIM / 4);
    uint32_t* d4 = (uint32_t*)dst + (size_t)row * (D_DIM / 4);   // row base
    float s = 0.0f;
#pragma unroll
    for (int c = 0; c < 3; c++) {
        const int wf = c * 64 + lane;            // word index in row (0..191)
        float4 v = s4[wf];
        s += v.x * v.x + v.y * v.y + v.z * v.z + v.w * v.w;
        union { uint32_t u; uint8_t b[4]; } pk;
        pk.b[0] = __hip_fp8_e4m3(v.x).__x;
        pk.b[1] = __hip_fp8_e4m3(v.y).__x;
        pk.b[2] = __hip_fp8_e4m3(v.z).__x;
        pk.b[3] = __hip_fp8_e4m3(v.w).__x;
        const int kb = wf >> 4, w16 = wf & 15;
        const int gw = w16 >> 1, h = w16 & 1;
        const int gp = ((gw & 3) << 1) | (gw >> 2);     // [0,4,1,5,2,6,3,7] order
        d4[(kb << 4) + (gp << 1) + h] = pk.u;           // relative to row base
    }
    for (int off = 32; off; off >>= 1) s += __shfl_down(s, off);
    if (lane == 0) {
        nrm[row] = s;
        if (blockIdx.y == 0) S[row] = 0.0f;
    }
}

// ---------------- kernel 2: triple-buffered fp8 MFMA GEMM + softmax epilogue -----
__device__ __forceinline__ void g2l16(const void* g, void* l) {
    __builtin_amdgcn_global_load_lds(
        (const __attribute__((address_space(1))) void*)g,
        (__attribute__((address_space(3))) void*)l, 16, 0, 0);
}

__global__ __launch_bounds__(512, 4) void gemm_fused(
        const uint8_t* __restrict__ A8, const uint8_t* __restrict__ P8,
        const float* __restrict__ a2, const float* __restrict__ p2,
        float* __restrict__ S, float* __restrict__ Dd) {
    __shared__ __align__(16) uint8_t As[3 * ABUF];   // 3 x 16 KB
    __shared__ __align__(16) uint8_t Bs[3 * BBUF];   // 3 x 8 KB

    // XCD-bijective swizzle: 512 blocks round-robin across 8 XCDs; XCD x gets the
    // contiguous swz range [x*64,(x+1)*64) = 4 B-panels x all 16 A-panels.
    const int lin = blockIdx.x;
    const int swz = (lin & 7) * 64 + (lin >> 3);
    const int bm = swz & 15, bn = swz >> 4;          // bm: 256-row A panel, bn: 128-row B panel

    const int t = threadIdx.x;
    const int lane = t & 63, wave = t >> 6;          // 8 waves
    const int wm = wave >> 1, wn = wave & 1;         // 4x2 waves, 64x64 tiles

    f32x4 acc[4][4];
#pragma unroll
    for (int i = 0; i < 4; i++)
#pragma unroll
        for (int j = 0; j < 4; j++) acc[i][j] = (f32x4){0.f, 0.f, 0.f, 0.f};

    // staging: chunk q = c*512 + t -> LDS row r = q>>2 = c*128 + (t>>2), slot t&3.
    // Stored global chunk g: slot = (g + (r>>1))&3 -> g = ((t&3) - (t>>3)) & 3
    // (c-invariant: c*128 rows -> (r>>1) shifts by 64 == 0 mod 4).
    const int gT = ((t & 3) - (t >> 3)) & 3;
    const size_t aBase = (size_t)(bm * 256 + (t >> 2)) * D_DIM + (size_t)gT * 16;
    const size_t bBase = (size_t)(bn * 128 + (t >> 2)) * D_DIM + (size_t)gT * 16;

    // LDS->frag read offsets (bytes). Row stride 64 B. Lane quad fq reads stored
    // chunk fq of its row at slot (fq + (R>>1))&3; b128 low 8B = k-step0 granule,
    // high 8B = k-step1 granule. Measured 0 conflicts (R14/R15/R18).
    const int fr = lane & 15, fq = lane >> 4;
    int aOff[4], bOff[4];
#pragma unroll
    for (int mi = 0; mi < 4; mi++) {
        const int R = wm * 64 + mi * 16 + fr;        // 0..255
        aOff[mi] = R * 64 + ((fq + (R >> 1)) & 3) * 16;
    }
#pragma unroll
    for (int ni = 0; ni < 4; ni++) {
        const int R = wn * 64 + ni * 16 + fr;        // 0..127
        bOff[ni] = R * 64 + ((fq + (R >> 1)) & 3) * 16;
    }

#define STAGE(K2, SEL)                                                            \
    do {                                                                          \
        const int k0_ = (K2) * 64;                                                \
        _Pragma("unroll")                                                         \
        for (int c = 0; c < 2; c++)                                               \
            g2l16(A8 + aBase + (size_t)c * (128 * D_DIM) + k0_,                   \
                  &As[(SEL) * ABUF + (c * 512 + t) * 16]);                        \
        g2l16(P8 + bBase + k0_, &Bs[(SEL) * BBUF + t * 16]);                      \
    } while (0)

    STAGE(0, 0);
    STAGE(1, 1);

    int s0 = 0;                                  // buffer holding tile k
    for (int k = 0; k < NITER; k++) {
        // Drain tile k's 3 loads (issued at iter k-2, ~2 iterations of lead);
        // tile k+1's 3 loads stay in flight across the barrier.
        if (k == NITER - 1) asm volatile("s_waitcnt vmcnt(0)" ::: "memory");
        else                asm volatile("s_waitcnt vmcnt(3)" ::: "memory");
        asm volatile("s_barrier" ::: "memory");
        if (k + 2 < NITER) {
            int s2 = s0 + 2; if (s2 >= 3) s2 -= 3;
            STAGE(k + 2, s2);                    // WAR-safe: buf read in iter k-1
        }

        const int lbA = s0 * ABUF, lbB = s0 * BBUF;
        i32x4 av[4], bv[4];
#pragma unroll
        for (int mi = 0; mi < 4; mi++)
            av[mi] = *(const i32x4*)&As[lbA + aOff[mi]];
#pragma unroll
        for (int ni = 0; ni < 4; ni++)
            bv[ni] = *(const i32x4*)&Bs[lbB + bOff[ni]];
#pragma unroll
        for (int step = 0; step < 2; step++) {
#pragma unroll
            for (int mi = 0; mi < 4; mi++) {
                const long long afh = ((const long long*)&av[mi])[step];
#pragma unroll
                for (int ni = 0; ni < 4; ni++) {
                    const long long bfh = ((const long long*)&bv[ni])[step];
                    acc[mi][ni] = __builtin_amdgcn_mfma_f32_16x16x32_fp8_fp8(
                        afh, bfh, acc[mi][ni], 0, 0, 0);
                }
            }
        }
        s0 = (s0 == 2) ? 0 : s0 + 1;
    }
#undef STAGE

    // ---- epilogue: dist -> exp(-dist), per-row partial sums, diagonal capture ----
    // C/D layout (16x16, shape-determined): col = lane&15, row = (lane>>4)*4 + reg
    float p2v[4];
#pragma unroll
    for (int ni = 0; ni < 4; ni++)
        p2v[ni] = p2[bn * 128 + wn * 64 + ni * 16 + fr];
    const int colBase = bn * 128 + wn * 64 + fr;

#pragma unroll
    for (int mi = 0; mi < 4; mi++) {
#pragma unroll
        for (int r = 0; r < 4; r++) {
            const int gi = bm * 256 + wm * 64 + mi * 16 + fq * 4 + r;
            const float a2v = a2[gi];
            float rs = 0.0f;
#pragma unroll
            for (int ni = 0; ni < 4; ni++) {
                const float cross = acc[mi][ni][r];
                const float sq = a2v + p2v[ni] - 2.0f * cross;
                const float dist = sqrtf(fmaxf(sq, 0.0f) + 1e-12f);
                const int gj = colBase + ni * 16;
                if (gi == gj) Dd[gi] = dist;
                rs += __expf(-dist);
            }
            rs += __shfl_xor(rs, 1);
            rs += __shfl_xor(rs, 2);
            rs += __shfl_xor(rs, 4);
            rs += __shfl_xor(rs, 8);
            if (fr == 0) atomicAdd(&S[gi], rs);
        }
    }
}

// ---------------- kernel 3: final reduce -> scalar -------------------------------
__global__ __launch_bounds__(1024) void finalize(
        const float* __restrict__ S, const float* __restrict__ Dd,
        float* __restrict__ out) {
    const int t = threadIdx.x;
    float s = 0.0f;
    for (int i = t; i < N_ROWS; i += 1024) s += Dd[i] + logf(S[i]);
    for (int off = 32; off; off >>= 1) s += __shfl_down(s, off);
    __shared__ float wsum[16];
    if ((t & 63) == 0) wsum[t >> 6] = s;
    __syncthreads();
    if (t == 0) {
        float acc = 0.0f;
#pragma unroll
        for (int w = 0; w < 16; w++) acc += wsum[w];
        out[0] = acc * (1.0f / N_ROWS);
    }
}

// ---------------- fallback (undersized workspace): naive fp32 --------------------
__global__ void zero_out1(float* __restrict__ out) {
    if (threadIdx.x == 0 && blockIdx.x == 0) out[0] = 0.0f;
}
__global__ void naive_row(const float* __restrict__ A, const float* __restrict__ P,
                          float* __restrict__ out) {
    __shared__ float arow[D_DIM];
    const int i = blockIdx.x, t = threadIdx.x;
    for (int c = t; c < D_DIM; c += 256) arow[c] = A[(size_t)i * D_DIM + c];
    __syncthreads();
    float sumexp = 0.0f, ddiag = 0.0f;
    for (int j = t; j < N_ROWS; j += 256) {
        const float* p = P + (size_t)j * D_DIM;
        float d2 = 0.0f;
        for (int c = 0; c < D_DIM; c++) { float df = arow[c] - p[c]; d2 += df * df; }
        float dist = sqrtf(fmaxf(d2, 0.0f) + 1e-12f);
        if (j == i) ddiag = dist;
        sumexp += __expf(-dist);
    }
    for (int off = 32; off; off >>= 1) {
        sumexp += __shfl_down(sumexp, off);
        ddiag  += __shfl_down(ddiag, off);
    }
    __shared__ float w1[4], w2[4];
    if ((t & 63) == 0) { w1[t >> 6] = sumexp; w2[t >> 6] = ddiag; }
    __syncthreads();
    if (t == 0) {
        float se = w1[0] + w1[1] + w1[2] + w1[3];
        float dd = w2[0] + w2[1] + w2[2] + w2[3];
        atomicAdd(out, (dd + logf(se)) * (1.0f / N_ROWS));
    }
}

extern "C" void kernel_launch(void* const* d_in, const int* in_sizes, int n_in,
                              void* d_out, int out_size, void* d_ws, size_t ws_size,
                              hipStream_t stream) {
    const float* A = (const float*)d_in[0];
    const float* P = (const float*)d_in[1];
    float* out = (float*)d_out;

    const size_t F8_BYTES = (size_t)N_ROWS * D_DIM;          // 3145728 per matrix
    const size_t V_BYTES  = (size_t)N_ROWS * sizeof(float);  // 16384
    const size_t NEED = 2 * F8_BYTES + 4 * V_BYTES;

    if (ws_size >= NEED) {
        char* ws = (char*)d_ws;
        uint8_t* A8 = (uint8_t*)(ws);
        uint8_t* P8 = (uint8_t*)(ws + F8_BYTES);
        float* a2 = (float*)(ws + 2 * F8_BYTES);
        float* p2 = (float*)(ws + 2 * F8_BYTES + V_BYTES);
        float* S  = (float*)(ws + 2 * F8_BYTES + 2 * V_BYTES);
        float* Dd = (float*)(ws + 2 * F8_BYTES + 3 * V_BYTES);

        hipLaunchKernelGGL(cvt_norms, dim3(N_ROWS / 4, 2), dim3(256), 0, stream,
                           A, P, A8, P8, a2, p2, S);
        hipLaunchKernelGGL(gemm_fused, dim3(512), dim3(512), 0, stream,
                           A8, P8, a2, p2, S, Dd);
        hipLaunchKernelGGL(finalize, dim3(1), dim3(1024), 0, stream, S, Dd, out);
    } else {
        hipLaunchKernelGGL(zero_out1, dim3(1), dim3(64), 0, stream, out);
        hipLaunchKernelGGL(naive_row, dim3(N_ROWS), dim3(256), 0, stream, A, P, out);
    }
}